// Round 5
// baseline (362.545 us; speedup 1.0000x reference)
//
#include <hip/hip_runtime.h>

typedef unsigned short u16;
typedef unsigned int u32;
typedef __attribute__((ext_vector_type(8))) short short8;   // 8 x bf16
typedef __attribute__((ext_vector_type(4))) float f32x4;

// ---------------- workspace layout (bytes) ----------------
#define OFF_WM    0         // float[801]: wmean[0..799] (pad 0), [800]=mean(b_in)
#define OFF_WINF  3584      // u16 [25][8][64][8]  W_in B-fragment-linear   (204800 B)
#define OFF_WEGF  208384    // u16 [6][17][64][8]  experts+gate frag-linear (104448 B)
#define OFF_WCTXF 312832    // u16 [2][8][64][8]   W_ctx frag-linear        (16384 B)
#define OFF_WOUTF 329216    // u16 [4][64][8]      W_out frag-linear        (4096 B)

__device__ __forceinline__ u16 f2bf(float x) {
  union { float f; u32 u; } v; v.f = x;
  u32 r = v.u + 0x7FFFu + ((v.u >> 16) & 1u);   // RNE
  return (u16)(r >> 16);
}

// ------------------------------------------------------------------
// Prep: wmean for the exact fp32 t path; all weights -> bf16 in
// MFMA-B-fragment-linear order: frag[tile][lane][j] with
// k = kt*32 + (lane>>4)*8 + j, n = ct*16 + (lane&15).
// ------------------------------------------------------------------
__global__ void prep_kernel(const float* __restrict__ W_in, const float* __restrict__ b_in,
                            const float* __restrict__ W_gate, const float* __restrict__ W_exp,
                            const float* __restrict__ W_ctx, const float* __restrict__ W_out,
                            float* __restrict__ wm, u16* __restrict__ WinF,
                            u16* __restrict__ WegF, u16* __restrict__ WctxF,
                            u16* __restrict__ WoutF) {
  int idx = blockIdx.x * 256 + threadIdx.x;
  if (idx < 801) {
    if (idx == 800) {
      float s = 0.f;
      for (int j = 0; j < 128; ++j) s += b_in[j];
      wm[800] = s * (1.f / 128.f);
    } else if (idx >= 784) {
      wm[idx] = 0.f;
    } else {
      float s = 0.f;
      for (int j = 0; j < 128; ++j) s += W_in[idx * 128 + j];
      wm[idx] = s * (1.f / 128.f);
    }
  } else if (idx < 103201) {                    // WinF: 25*8 tiles
    int f = idx - 801;
    int j = f & 7, lane = (f >> 3) & 63, tile = f >> 9;
    int ct = tile & 7, kt = tile >> 3;
    int k = kt * 32 + ((lane >> 4) << 3) + j;
    int n = ct * 16 + (lane & 15);
    WinF[f] = (k < 784) ? f2bf(W_in[k * 128 + n]) : (u16)0;
  } else if (idx < 155425) {                    // WegF: 6*17 tiles
    int f = idx - 103201;
    int j = f & 7, lane = (f >> 3) & 63, tile = f >> 9;
    int kt = tile / 17, ct = tile - kt * 17;
    int k = kt * 32 + ((lane >> 4) << 3) + j;
    int n = ct * 16 + (lane & 15);
    float v = 0.f;
    if (n < 256) { int e = n >> 6, h = n & 63; v = W_exp[(e * 192 + k) * 64 + h]; }
    else if (n < 260) v = W_gate[k * 4 + (n - 256)];
    WegF[f] = f2bf(v);
  } else if (idx < 163617) {                    // WctxF: 2*8 tiles
    int f = idx - 155425;
    int j = f & 7, lane = (f >> 3) & 63, tile = f >> 9;
    int ct = tile & 7, kt = tile >> 3;
    int k = kt * 32 + ((lane >> 4) << 3) + j;
    int n = ct * 16 + (lane & 15);
    WctxF[f] = f2bf(W_ctx[k * 128 + n]);
  } else if (idx < 165665) {                    // WoutF: 4 tiles (N padded 3->16)
    int f = idx - 163617;
    int j = f & 7, lane = (f >> 3) & 63, kt = f >> 9;
    int k = kt * 32 + ((lane >> 4) << 3) + j;
    int n = lane & 15;
    WoutF[f] = (n < 3) ? f2bf(W_out[k * 3 + n]) : (u16)0;
  }
}

// ------------------------------------------------------------------
// Fused forward, barrier-free: 4 waves/WG, each wave owns 64 rows
// (FOUR 16-row MFMA groups) and loads every weight fragment ONCE for
// all four groups. Scaling law from rounds 3->4: per-wave duration is
// a fixed chain of serialized load->wait stages, ~independent of rows
// per stage -> amortize the chain over more rows. Weight loads per
// row halve again vs round 4.
//
// Per-wave private LDS: four groups x 3840 u16 (7680 B each):
//   enh  [6][16][40]  (full group block)      -- phase 1 -> phase 2
//   cmb  [2][16][40]  (aliases u16 [0,1280))  -- phase 2 -> phase 3
//   ctx  [16][136]    (aliases u16 [1280,3456)) -- phase 3 -> phase 4
// Aliasing is safe: same-wave DS ops are processed in order.
// LDS/block = 4*4*7680 = 122880 B -> 1 block/CU (grid is exactly
// 256 blocks). Phases 2 and 3 process groups in two pairs to cap
// live accumulator registers (phase-1 peak ~214 VGPR, cap 512 via
// __launch_bounds__(256,1): no spill).
// ------------------------------------------------------------------
__global__ __launch_bounds__(256, 1)
void fused_kernel(const float* __restrict__ x,
                  const float* __restrict__ b_in, const float* __restrict__ b_gate,
                  const float* __restrict__ b_exp, const float* __restrict__ b_ctx,
                  const float* __restrict__ b_out,
                  const float* __restrict__ wm, const u16* __restrict__ WinF,
                  const u16* __restrict__ WegF, const u16* __restrict__ WctxF,
                  const u16* __restrict__ WoutF,
                  float* __restrict__ out) {
  __shared__ __align__(16) u16 smem[4 * 15360];
  const int tid = threadIdx.x;
  const int wv = tid >> 6;
  const int ln = tid & 63;
  const int cb = ln & 15;        // fragment col / A-row
  const int qr = ln >> 4;        // k-quad

  u16* eh[4];
  #pragma unroll
  for (int g = 0; g < 4; ++g) eh[g] = smem + wv * 15360 + g * 3840;

  const int grow = blockIdx.x * 256 + wv * 64;    // this wave's first row
  const float* xrs[4];
  #pragma unroll
  for (int g = 0; g < 4; ++g) xrs[g] = x + (size_t)(grow + g * 16 + cb) * 784;

  const f32x4 vz = {0.f, 0.f, 0.f, 0.f};

  // ---- Phase 1: projected = x @ W_in (MFMA) + exact fp32 t, 4 row-groups ----
  f32x4 acc[4][8];
  #pragma unroll
  for (int g = 0; g < 4; ++g)
    #pragma unroll
    for (int i = 0; i < 8; ++i) acc[g][i] = vz;
  float tp[4] = {0.f, 0.f, 0.f, 0.f};

  const u16* wbase = WinF + ln * 8;
  for (int kt = 0; kt < 25; ++kt) {
    // one weight-fragment stream serves all FOUR row groups
    const u16* wb = wbase + (size_t)kt * 4096;
    short8 Bf[8];
    #pragma unroll
    for (int ct = 0; ct < 8; ++ct)
      Bf[ct] = *(const short8*)(wb + ct * 512);

    const int k0 = kt * 32 + qr * 8;
    short8 afs[4];
    if (k0 < 784) {                       // K-tail: zero A (WinF pad also 0)
      const float4 m0 = *(const float4*)(wm + k0);
      const float4 m1 = *(const float4*)(wm + k0 + 4);
      #pragma unroll
      for (int g = 0; g < 4; ++g) {
        float4 a0 = *(const float4*)(xrs[g] + k0);
        float4 a1 = *(const float4*)(xrs[g] + k0 + 4);
        tp[g] += a0.x * m0.x + a0.y * m0.y + a0.z * m0.z + a0.w * m0.w
               + a1.x * m1.x + a1.y * m1.y + a1.z * m1.z + a1.w * m1.w;
        union { short8 s; u32 u[4]; } af;
        af.u[0] = (u32)f2bf(a0.x) | ((u32)f2bf(a0.y) << 16);
        af.u[1] = (u32)f2bf(a0.z) | ((u32)f2bf(a0.w) << 16);
        af.u[2] = (u32)f2bf(a1.x) | ((u32)f2bf(a1.y) << 16);
        af.u[3] = (u32)f2bf(a1.z) | ((u32)f2bf(a1.w) << 16);
        afs[g] = af.s;
      }
    } else {
      #pragma unroll
      for (int g = 0; g < 4; ++g) afs[g] = short8{0,0,0,0,0,0,0,0};
    }

    #pragma unroll
    for (int ct = 0; ct < 8; ++ct) {
      #pragma unroll
      for (int g = 0; g < 4; ++g)
        acc[g][ct] = __builtin_amdgcn_mfma_f32_16x16x32_bf16(afs[g], Bf[ct], acc[g][ct], 0, 0, 0);
    }
  }

  // t: reduce partials across the 4 k-quads of row cb
  #pragma unroll
  for (int g = 0; g < 4; ++g) {
    tp[g] += __shfl_xor(tp[g], 16);
    tp[g] += __shfl_xor(tp[g], 32);
  }
  const float mb = wm[800];

  // enhanced[cols 0..127] = projected + b_in  (bf16, chunked [6][16][40])
  #pragma unroll
  for (int ct = 0; ct < 8; ++ct) {
    float bi = b_in[ct * 16 + cb];
    #pragma unroll
    for (int g = 0; g < 4; ++g) {
      u16* dst = eh[g] + (ct >> 1) * 640 + (ct & 1) * 16 + cb;
      #pragma unroll
      for (int i = 0; i < 4; ++i)
        dst[(qr * 4 + i) * 40] = f2bf(acc[g][ct][i] + bi);
    }
  }
  // enhanced[cols 128..191] = phasor bank, per group.
  #pragma unroll
  for (int g = 0; g < 4; ++g) {
    float t = tp[g] + mb;
    float phi = 7.f * t;
    float ss, cc, sd, cd;
    sincosf(phi * (float)(qr * 8 + 1), &ss, &cc);
    sincosf(phi, &sd, &cd);
    u16* pc = eh[g] + 4 * 640 + cb * 40 + qr * 8;
    u16* ps = eh[g] + 5 * 640 + cb * 40 + qr * 8;
    #pragma unroll
    for (int m = 0; m < 8; ++m) {
      pc[m] = f2bf(cc);
      ps[m] = f2bf(ss);
      float nc = cc * cd - ss * sd;
      ss = ss * cd + cc * sd;
      cc = nc;
    }
  }

  // ---- Phase 2: gate + experts, processed in two group-pairs ----
  const u16* gbase = WegF + ln * 8;
  #pragma unroll
  for (int p = 0; p < 2; ++p) {
    u16* e0 = eh[2 * p];
    u16* e1 = eh[2 * p + 1];

    // gate pass (tile 16)
    f32x4 g0 = vz, g1 = vz;
    #pragma unroll
    for (int kt = 0; kt < 6; ++kt) {
      short8 A0 = *(const short8*)(e0 + kt * 640 + cb * 40 + qr * 8);
      short8 A1 = *(const short8*)(e1 + kt * 640 + cb * 40 + qr * 8);
      short8 Bg = *(const short8*)(gbase + (size_t)(kt * 17 + 16) * 512);
      g0 = __builtin_amdgcn_mfma_f32_16x16x32_bf16(A0, Bg, g0, 0, 0, 0);
      g1 = __builtin_amdgcn_mfma_f32_16x16x32_bf16(A1, Bg, g1, 0, 0, 0);
    }

    // softmax over expert lanes cb=0..3 of each quad, broadcast to all lanes
    float ge0[4][4], ge1[4][4];            // [expert][i]
    {
      float bg = b_gate[cb & 3];
      #pragma unroll
      for (int i = 0; i < 4; ++i) {
        {
          float gi = g0[i] + bg;
          float mx = fmaxf(gi, __shfl_xor(gi, 1));
          mx = fmaxf(mx, __shfl_xor(mx, 2));
          float ev = __expf(gi - mx);
          float sv = ev + __shfl_xor(ev, 1);
          sv += __shfl_xor(sv, 2);
          float g = ev / sv;
          int base = qr * 16;
          ge0[0][i] = __shfl(g, base + 0);
          ge0[1][i] = __shfl(g, base + 1);
          ge0[2][i] = __shfl(g, base + 2);
          ge0[3][i] = __shfl(g, base + 3);
        }
        {
          float gi = g1[i] + bg;
          float mx = fmaxf(gi, __shfl_xor(gi, 1));
          mx = fmaxf(mx, __shfl_xor(mx, 2));
          float ev = __expf(gi - mx);
          float sv = ev + __shfl_xor(ev, 1);
          sv += __shfl_xor(sv, 2);
          float g = ev / sv;
          int base = qr * 16;
          ge1[0][i] = __shfl(g, base + 0);
          ge1[1][i] = __shfl(g, base + 1);
          ge1[2][i] = __shfl(g, base + 2);
          ge1[3][i] = __shfl(g, base + 3);
        }
      }
    }

    // experts one at a time (caps live AGPRs), combine incrementally
    f32x4 cA[4], cB[4];
    #pragma unroll
    for (int i = 0; i < 4; ++i) { cA[i] = vz; cB[i] = vz; }
    #pragma unroll
    for (int e = 0; e < 4; ++e) {
      f32x4 ae0[4], ae1[4];
      #pragma unroll
      for (int i = 0; i < 4; ++i) { ae0[i] = vz; ae1[i] = vz; }
      #pragma unroll
      for (int kt = 0; kt < 6; ++kt) {
        short8 A0 = *(const short8*)(e0 + kt * 640 + cb * 40 + qr * 8);
        short8 A1 = *(const short8*)(e1 + kt * 640 + cb * 40 + qr * 8);
        const u16* gb = gbase + (size_t)(kt * 17 + e * 4) * 512;
        #pragma unroll
        for (int c2 = 0; c2 < 4; ++c2) {
          short8 Bf = *(const short8*)(gb + c2 * 512);
          ae0[c2] = __builtin_amdgcn_mfma_f32_16x16x32_bf16(A0, Bf, ae0[c2], 0, 0, 0);
          ae1[c2] = __builtin_amdgcn_mfma_f32_16x16x32_bf16(A1, Bf, ae1[c2], 0, 0, 0);
        }
      }
      #pragma unroll
      for (int c2 = 0; c2 < 4; ++c2) {
        float be = b_exp[e * 64 + c2 * 16 + cb];
        #pragma unroll
        for (int i = 0; i < 4; ++i) {
          cA[c2][i] += ge0[e][i] * fmaxf(ae0[c2][i] + be, 0.f);
          cB[c2][i] += ge1[e][i] * fmaxf(ae1[c2][i] + be, 0.f);
        }
      }
    }
    // combined -> LDS (bf16, [2][16][40]); this pair's enh reads all precede
    #pragma unroll
    for (int c2 = 0; c2 < 4; ++c2) {
      u16* d0 = e0 + (c2 >> 1) * 640 + (c2 & 1) * 16 + cb;
      u16* d1 = e1 + (c2 >> 1) * 640 + (c2 & 1) * 16 + cb;
      #pragma unroll
      for (int i = 0; i < 4; ++i) {
        d0[(qr * 4 + i) * 40] = f2bf(cA[c2][i]);
        d1[(qr * 4 + i) * 40] = f2bf(cB[c2][i]);
      }
    }
  }

  // ---- Phase 3: ctx = tanh(combined @ W_ctx + b_ctx), K=64, two pairs ----
  #pragma unroll
  for (int p = 0; p < 2; ++p) {
    u16* e0 = eh[2 * p];
    u16* e1 = eh[2 * p + 1];
    f32x4 c30[8], c31[8];
    #pragma unroll
    for (int i = 0; i < 8; ++i) { c30[i] = vz; c31[i] = vz; }
    #pragma unroll
    for (int kt = 0; kt < 2; ++kt) {
      short8 A0 = *(const short8*)(e0 + kt * 640 + cb * 40 + qr * 8);
      short8 A1 = *(const short8*)(e1 + kt * 640 + cb * 40 + qr * 8);
      #pragma unroll
      for (int ct = 0; ct < 8; ++ct) {
        short8 Bf = *(const short8*)(WctxF + ((kt * 8 + ct) * 64 + ln) * 8);
        c30[ct] = __builtin_amdgcn_mfma_f32_16x16x32_bf16(A0, Bf, c30[ct], 0, 0, 0);
        c31[ct] = __builtin_amdgcn_mfma_f32_16x16x32_bf16(A1, Bf, c31[ct], 0, 0, 0);
      }
    }
    #pragma unroll
    for (int ct = 0; ct < 8; ++ct) {
      float bc = b_ctx[ct * 16 + cb];
      u16* d0 = e0 + 1280 + ct * 16 + cb;
      u16* d1 = e1 + 1280 + ct * 16 + cb;
      #pragma unroll
      for (int i = 0; i < 4; ++i) {
        float v0 = c30[ct][i] + bc;
        float x0 = __expf(2.f * v0);         // tanh via exp; saturates correctly
        d0[(qr * 4 + i) * 136] = f2bf(1.f - 2.f / (x0 + 1.f));
        float v1 = c31[ct][i] + bc;
        float x1 = __expf(2.f * v1);
        d1[(qr * 4 + i) * 136] = f2bf(1.f - 2.f / (x1 + 1.f));
      }
    }
  }

  // ---- Phase 4: logits = ctx @ W_out + b_out (MFMA, N padded to 16) ----
  f32x4 a4[4];
  #pragma unroll
  for (int g = 0; g < 4; ++g) a4[g] = vz;
  #pragma unroll
  for (int kt = 0; kt < 4; ++kt) {
    short8 Bf = *(const short8*)(WoutF + (kt * 64 + ln) * 8);
    #pragma unroll
    for (int g = 0; g < 4; ++g) {
      short8 A = *(const short8*)(eh[g] + 1280 + cb * 136 + kt * 32 + qr * 8);
      a4[g] = __builtin_amdgcn_mfma_f32_16x16x32_bf16(A, Bf, a4[g], 0, 0, 0);
    }
  }
  if (cb < 3) {
    float bo = b_out[cb];
    #pragma unroll
    for (int g = 0; g < 4; ++g)
      #pragma unroll
      for (int i = 0; i < 4; ++i)
        out[(size_t)(grow + g * 16 + qr * 4 + i) * 3 + cb] = a4[g][i] + bo;
  }
}

extern "C" void kernel_launch(void* const* d_in, const int* in_sizes, int n_in,
                              void* d_out, int out_size, void* d_ws, size_t ws_size,
                              hipStream_t stream) {
  const float* x      = (const float*)d_in[0];
  const float* W_in   = (const float*)d_in[1];
  const float* b_in   = (const float*)d_in[2];
  const float* W_gate = (const float*)d_in[3];
  const float* b_gate = (const float*)d_in[4];
  const float* W_exp  = (const float*)d_in[5];
  const float* b_exp  = (const float*)d_in[6];
  const float* W_ctx  = (const float*)d_in[7];
  const float* b_ctx  = (const float*)d_in[8];
  const float* W_out  = (const float*)d_in[9];
  const float* b_out  = (const float*)d_in[10];
  float* out = (float*)d_out;

  char* ws = (char*)d_ws;
  float* wm  = (float*)(ws + OFF_WM);
  u16* WinF  = (u16*)(ws + OFF_WINF);
  u16* WegF  = (u16*)(ws + OFF_WEGF);
  u16* WctxF = (u16*)(ws + OFF_WCTXF);
  u16* WoutF = (u16*)(ws + OFF_WOUTF);

  const int B = in_sizes[0] / 784;
  prep_kernel<<<648, 256, 0, stream>>>(W_in, b_in, W_gate, W_exp, W_ctx, W_out,
                                       wm, WinF, WegF, WctxF, WoutF);
  fused_kernel<<<B / 256, 256, 0, stream>>>(x, b_in, b_gate, b_exp, b_ctx, b_out,
                                            wm, WinF, WegF, WctxF, WoutF, out);
}

// Round 6
// 329.000 us; speedup vs baseline: 1.1020x; 1.1020x over previous
//
#include <hip/hip_runtime.h>

typedef unsigned short u16;
typedef unsigned int u32;
typedef __attribute__((ext_vector_type(8))) short short8;   // 8 x bf16
typedef __attribute__((ext_vector_type(4))) float f32x4;

// ---------------- workspace layout (bytes) ----------------
#define OFF_WM    0         // float[801]: wmean[0..799] (pad 0), [800]=mean(b_in)
#define OFF_WINF  3584      // u16 [25][8][64][8]  W_in B-fragment-linear   (204800 B)
#define OFF_WEGF  208384    // u16 [6][17][64][8]  experts+gate frag-linear (104448 B)
#define OFF_WCTXF 312832    // u16 [2][8][64][8]   W_ctx frag-linear        (16384 B)
#define OFF_WOUTF 329216    // u16 [4][64][8]      W_out frag-linear        (4096 B)

__device__ __forceinline__ u16 f2bf(float x) {
  union { float f; u32 u; } v; v.f = x;
  u32 r = v.u + 0x7FFFu + ((v.u >> 16) & 1u);   // RNE
  return (u16)(r >> 16);
}

// ------------------------------------------------------------------
// Prep: wmean for the exact fp32 t path; all weights -> bf16 in
// MFMA-B-fragment-linear order: frag[tile][lane][j] with
// k = kt*32 + (lane>>4)*8 + j, n = ct*16 + (lane&15).
// ------------------------------------------------------------------
__global__ void prep_kernel(const float* __restrict__ W_in, const float* __restrict__ b_in,
                            const float* __restrict__ W_gate, const float* __restrict__ W_exp,
                            const float* __restrict__ W_ctx, const float* __restrict__ W_out,
                            float* __restrict__ wm, u16* __restrict__ WinF,
                            u16* __restrict__ WegF, u16* __restrict__ WctxF,
                            u16* __restrict__ WoutF) {
  int idx = blockIdx.x * 256 + threadIdx.x;
  if (idx < 801) {
    if (idx == 800) {
      float s = 0.f;
      for (int j = 0; j < 128; ++j) s += b_in[j];
      wm[800] = s * (1.f / 128.f);
    } else if (idx >= 784) {
      wm[idx] = 0.f;
    } else {
      float s = 0.f;
      for (int j = 0; j < 128; ++j) s += W_in[idx * 128 + j];
      wm[idx] = s * (1.f / 128.f);
    }
  } else if (idx < 103201) {                    // WinF: 25*8 tiles
    int f = idx - 801;
    int j = f & 7, lane = (f >> 3) & 63, tile = f >> 9;
    int ct = tile & 7, kt = tile >> 3;
    int k = kt * 32 + ((lane >> 4) << 3) + j;
    int n = ct * 16 + (lane & 15);
    WinF[f] = (k < 784) ? f2bf(W_in[k * 128 + n]) : (u16)0;
  } else if (idx < 155425) {                    // WegF: 6*17 tiles
    int f = idx - 103201;
    int j = f & 7, lane = (f >> 3) & 63, tile = f >> 9;
    int kt = tile / 17, ct = tile - kt * 17;
    int k = kt * 32 + ((lane >> 4) << 3) + j;
    int n = ct * 16 + (lane & 15);
    float v = 0.f;
    if (n < 256) { int e = n >> 6, h = n & 63; v = W_exp[(e * 192 + k) * 64 + h]; }
    else if (n < 260) v = W_gate[k * 4 + (n - 256)];
    WegF[f] = f2bf(v);
  } else if (idx < 163617) {                    // WctxF: 2*8 tiles
    int f = idx - 155425;
    int j = f & 7, lane = (f >> 3) & 63, tile = f >> 9;
    int ct = tile & 7, kt = tile >> 3;
    int k = kt * 32 + ((lane >> 4) << 3) + j;
    int n = ct * 16 + (lane & 15);
    WctxF[f] = f2bf(W_ctx[k * 128 + n]);
  } else if (idx < 165665) {                    // WoutF: 4 tiles (N padded 3->16)
    int f = idx - 163617;
    int j = f & 7, lane = (f >> 3) & 63, kt = f >> 9;
    int k = kt * 32 + ((lane >> 4) << 3) + j;
    int n = lane & 15;
    WoutF[f] = (n < 3) ? f2bf(W_out[k * 3 + n]) : (u16)0;
  }
}

// ------------------------------------------------------------------
// Fused forward: 4 waves/WG, each wave owns 32 rows (two 16-row MFMA
// groups, the round-4 sweet spot). NEW: block-cooperative LDS staging
// of weight fragments. Rationale: rows/wave mapping showed per-SIMD
// time ~ max(latency exposure, per-SIMD load stream); round-4's 4
// waves/block each privately stream IDENTICAL weights (~320 KB/wave).
// Staging cuts per-block weight traffic 4x while keeping 2 waves/SIMD
// of TLP. x stays private (per-row, coalesced fp32).
//
// LDS (77824 B/block -> 2 blocks/CU):
//   per-wave enh: 2 groups x 3840 u16 (7680 u16/wave, 4 waves)
//     enh [6][16][40]; cmb aliases [0,1280); ctx aliases [1280,3456)
//     (same-wave DS ordering makes aliasing safe, as before)
//   stage: 8192 u16 shared. Phase 1: 2 x 4096 (double-buffered kt).
//     Phase 2: 16 expert tiles/kt (8192). Phase 3: all 16 W_ctx tiles.
//     Phase 4: 4 W_out tiles.
// Staging copy pattern: thread tid moves short8 chunks at u16 offset
// c*2048 + tid*8 -> 16 B/lane contiguous in global AND LDS (2-way
// bank alias = free).
// Barriers: uniform control flow only (lane-divergent k0<784 branch
// contains no barrier). ~45 __syncthreads total ~1-2 us.
// ------------------------------------------------------------------
__global__ __launch_bounds__(256, 2)
void fused_kernel(const float* __restrict__ x,
                  const float* __restrict__ b_in, const float* __restrict__ b_gate,
                  const float* __restrict__ b_exp, const float* __restrict__ b_ctx,
                  const float* __restrict__ b_out,
                  const float* __restrict__ wm, const u16* __restrict__ WinF,
                  const u16* __restrict__ WegF, const u16* __restrict__ WctxF,
                  const u16* __restrict__ WoutF,
                  float* __restrict__ out) {
  __shared__ __align__(16) u16 smem[4 * 7680 + 8192];
  const int tid = threadIdx.x;
  const int wv = tid >> 6;
  const int ln = tid & 63;
  const int cb = ln & 15;        // fragment col / A-row
  const int qr = ln >> 4;        // k-quad
  u16* enh0 = smem + wv * 7680;
  u16* enh1 = enh0 + 3840;
  u16* cmb0 = enh0;
  u16* cmb1 = enh1;
  u16* ctx0 = enh0 + 1280;
  u16* ctx1 = enh1 + 1280;
  u16* stg  = smem + 4 * 7680;   // 8192 u16 staging region

  const int grow = blockIdx.x * 128 + wv * 32;    // this wave's first row
  const float* xr0 = x + (size_t)(grow + cb) * 784;
  const float* xr1 = xr0 + (size_t)16 * 784;

  const f32x4 vz = {0.f, 0.f, 0.f, 0.f};

  // ---- Phase 1: projected = x @ W_in (MFMA) + exact fp32 t, 2 row-groups ----
  f32x4 acc0[8], acc1[8];
  #pragma unroll
  for (int i = 0; i < 8; ++i) { acc0[i] = vz; acc1[i] = vz; }
  float tp0 = 0.f, tp1 = 0.f;

  // prologue: stage kt=0 weight tiles into buffer 0
  {
    const u16* src = WinF + tid * 8;
    short8 r0 = *(const short8*)(src);
    short8 r1 = *(const short8*)(src + 2048);
    *(short8*)(stg + tid * 8) = r0;
    *(short8*)(stg + 2048 + tid * 8) = r1;
  }
  __syncthreads();

  for (int kt = 0; kt < 25; ++kt) {
    const int buf = (kt & 1) << 12;               // 0 or 4096 u16
    // prefetch next kt's tiles to registers (write to LDS after compute)
    short8 r0 = short8{0,0,0,0,0,0,0,0}, r1 = r0;
    const bool pf = (kt < 24);
    if (pf) {
      const u16* src = WinF + (size_t)(kt + 1) * 4096 + tid * 8;
      r0 = *(const short8*)(src);
      r1 = *(const short8*)(src + 2048);
    }

    const int k0 = kt * 32 + qr * 8;
    union { short8 s; u32 u[4]; } af, bf;
    {
      float4 a0 = make_float4(0.f, 0.f, 0.f, 0.f), a1 = a0;
      float4 b0 = a0, b1 = a0, m0 = a0, m1 = a0;
      if (k0 < 784) {                     // K-tail: zero A (staged pad also 0)
        a0 = *(const float4*)(xr0 + k0);
        a1 = *(const float4*)(xr0 + k0 + 4);
        b0 = *(const float4*)(xr1 + k0);
        b1 = *(const float4*)(xr1 + k0 + 4);
        m0 = *(const float4*)(wm + k0);
        m1 = *(const float4*)(wm + k0 + 4);
        tp0 += a0.x * m0.x + a0.y * m0.y + a0.z * m0.z + a0.w * m0.w
             + a1.x * m1.x + a1.y * m1.y + a1.z * m1.z + a1.w * m1.w;
        tp1 += b0.x * m0.x + b0.y * m0.y + b0.z * m0.z + b0.w * m0.w
             + b1.x * m1.x + b1.y * m1.y + b1.z * m1.z + b1.w * m1.w;
      }
      af.u[0] = (u32)f2bf(a0.x) | ((u32)f2bf(a0.y) << 16);
      af.u[1] = (u32)f2bf(a0.z) | ((u32)f2bf(a0.w) << 16);
      af.u[2] = (u32)f2bf(a1.x) | ((u32)f2bf(a1.y) << 16);
      af.u[3] = (u32)f2bf(a1.z) | ((u32)f2bf(a1.w) << 16);
      bf.u[0] = (u32)f2bf(b0.x) | ((u32)f2bf(b0.y) << 16);
      bf.u[1] = (u32)f2bf(b0.z) | ((u32)f2bf(b0.w) << 16);
      bf.u[2] = (u32)f2bf(b1.x) | ((u32)f2bf(b1.y) << 16);
      bf.u[3] = (u32)f2bf(b1.z) | ((u32)f2bf(b1.w) << 16);
    }

    // weight fragments from LDS (staged): ds_read_b128, 2-way alias = free
    short8 Bf[8];
    #pragma unroll
    for (int ct = 0; ct < 8; ++ct)
      Bf[ct] = *(const short8*)(stg + buf + ct * 512 + ln * 8);

    #pragma unroll
    for (int ct = 0; ct < 8; ++ct) {
      acc0[ct] = __builtin_amdgcn_mfma_f32_16x16x32_bf16(af.s, Bf[ct], acc0[ct], 0, 0, 0);
      acc1[ct] = __builtin_amdgcn_mfma_f32_16x16x32_bf16(bf.s, Bf[ct], acc1[ct], 0, 0, 0);
    }

    if (pf) {
      u16* dst = stg + (buf ^ 4096);
      *(short8*)(dst + tid * 8) = r0;
      *(short8*)(dst + 2048 + tid * 8) = r1;
    }
    __syncthreads();    // next-kt staging visible; prior buffer free to overwrite
  }

  // t: reduce partials across the 4 k-quads of row cb
  tp0 += __shfl_xor(tp0, 16);
  tp0 += __shfl_xor(tp0, 32);
  tp1 += __shfl_xor(tp1, 16);
  tp1 += __shfl_xor(tp1, 32);
  const float mb = wm[800];
  const float t0 = tp0 + mb;
  const float t1 = tp1 + mb;

  // enhanced[cols 0..127] = projected + b_in  (bf16, chunked [6][16][40])
  #pragma unroll
  for (int ct = 0; ct < 8; ++ct) {
    float bi = b_in[ct * 16 + cb];
    u16* d0 = enh0 + (ct >> 1) * 640 + (ct & 1) * 16 + cb;
    u16* d1 = enh1 + (ct >> 1) * 640 + (ct & 1) * 16 + cb;
    #pragma unroll
    for (int i = 0; i < 4; ++i) {
      d0[(qr * 4 + i) * 40] = f2bf(acc0[ct][i] + bi);
      d1[(qr * 4 + i) * 40] = f2bf(acc1[ct][i] + bi);
    }
  }
  // enhanced[cols 128..191] = phasor bank, per group.
  #pragma unroll
  for (int g = 0; g < 2; ++g) {
    float t = g ? t1 : t0;
    u16* eW = g ? enh1 : enh0;
    float phi = 7.f * t;
    float ss, cc, sd, cd;
    sincosf(phi * (float)(qr * 8 + 1), &ss, &cc);
    sincosf(phi, &sd, &cd);
    u16* pc = eW + 4 * 640 + cb * 40 + qr * 8;
    u16* ps = eW + 5 * 640 + cb * 40 + qr * 8;
    #pragma unroll
    for (int m = 0; m < 8; ++m) {
      pc[m] = f2bf(cc);
      ps[m] = f2bf(ss);
      float nc = cc * cd - ss * sd;
      ss = ss * cd + cc * sd;
      cc = nc;
    }
  }

  // ---- Phase 2: gate (private loads) then experts (staged per kt) ----
  const u16* gbase = WegF + ln * 8;
  f32x4 g0 = vz, g1 = vz;
  #pragma unroll
  for (int kt = 0; kt < 6; ++kt) {
    short8 A0 = *(const short8*)(enh0 + kt * 640 + cb * 40 + qr * 8);
    short8 A1 = *(const short8*)(enh1 + kt * 640 + cb * 40 + qr * 8);
    short8 Bg = *(const short8*)(gbase + (size_t)(kt * 17 + 16) * 512);
    g0 = __builtin_amdgcn_mfma_f32_16x16x32_bf16(A0, Bg, g0, 0, 0, 0);
    g1 = __builtin_amdgcn_mfma_f32_16x16x32_bf16(A1, Bg, g1, 0, 0, 0);
  }

  // softmax over expert lanes cb=0..3 of each quad, broadcast to all lanes
  float ge0[4][4], ge1[4][4];              // [expert][i]
  {
    float bg = b_gate[cb & 3];
    #pragma unroll
    for (int i = 0; i < 4; ++i) {
      {
        float gi = g0[i] + bg;
        float mx = fmaxf(gi, __shfl_xor(gi, 1));
        mx = fmaxf(mx, __shfl_xor(mx, 2));
        float ev = __expf(gi - mx);
        float sv = ev + __shfl_xor(ev, 1);
        sv += __shfl_xor(sv, 2);
        float g = ev / sv;
        int base = qr * 16;
        ge0[0][i] = __shfl(g, base + 0);
        ge0[1][i] = __shfl(g, base + 1);
        ge0[2][i] = __shfl(g, base + 2);
        ge0[3][i] = __shfl(g, base + 3);
      }
      {
        float gi = g1[i] + bg;
        float mx = fmaxf(gi, __shfl_xor(gi, 1));
        mx = fmaxf(mx, __shfl_xor(mx, 2));
        float ev = __expf(gi - mx);
        float sv = ev + __shfl_xor(ev, 1);
        sv += __shfl_xor(sv, 2);
        float g = ev / sv;
        int base = qr * 16;
        ge1[0][i] = __shfl(g, base + 0);
        ge1[1][i] = __shfl(g, base + 1);
        ge1[2][i] = __shfl(g, base + 2);
        ge1[3][i] = __shfl(g, base + 3);
      }
    }
  }

  // experts: kt-outer, 16 expert tiles staged per kt, shared by all waves
  f32x4 ae0[16], ae1[16];
  #pragma unroll
  for (int c = 0; c < 16; ++c) { ae0[c] = vz; ae1[c] = vz; }
  for (int kt = 0; kt < 6; ++kt) {
    __syncthreads();                    // prior stg readers done
    {
      const u16* src = WegF + (size_t)kt * 17 * 512 + tid * 8;
      short8 s0 = *(const short8*)(src);
      short8 s1 = *(const short8*)(src + 2048);
      short8 s2 = *(const short8*)(src + 4096);
      short8 s3 = *(const short8*)(src + 6144);
      *(short8*)(stg + tid * 8) = s0;
      *(short8*)(stg + 2048 + tid * 8) = s1;
      *(short8*)(stg + 4096 + tid * 8) = s2;
      *(short8*)(stg + 6144 + tid * 8) = s3;
    }
    __syncthreads();
    short8 A0 = *(const short8*)(enh0 + kt * 640 + cb * 40 + qr * 8);
    short8 A1 = *(const short8*)(enh1 + kt * 640 + cb * 40 + qr * 8);
    #pragma unroll
    for (int c = 0; c < 16; ++c) {
      short8 Bf = *(const short8*)(stg + c * 512 + ln * 8);
      ae0[c] = __builtin_amdgcn_mfma_f32_16x16x32_bf16(A0, Bf, ae0[c], 0, 0, 0);
      ae1[c] = __builtin_amdgcn_mfma_f32_16x16x32_bf16(A1, Bf, ae1[c], 0, 0, 0);
    }
  }

  // combined = sum_e gate_e * relu(expert_e)
  f32x4 cA[4], cB[4];
  #pragma unroll
  for (int i = 0; i < 4; ++i) { cA[i] = vz; cB[i] = vz; }
  #pragma unroll
  for (int e = 0; e < 4; ++e) {
    #pragma unroll
    for (int c2 = 0; c2 < 4; ++c2) {
      float be = b_exp[e * 64 + c2 * 16 + cb];
      #pragma unroll
      for (int i = 0; i < 4; ++i) {
        cA[c2][i] += ge0[e][i] * fmaxf(ae0[e * 4 + c2][i] + be, 0.f);
        cB[c2][i] += ge1[e][i] * fmaxf(ae1[e * 4 + c2][i] + be, 0.f);
      }
    }
  }
  // combined -> LDS (bf16, [2][16][40]); same-wave enh reads all precede
  #pragma unroll
  for (int c2 = 0; c2 < 4; ++c2) {
    u16* d0 = cmb0 + (c2 >> 1) * 640 + (c2 & 1) * 16 + cb;
    u16* d1 = cmb1 + (c2 >> 1) * 640 + (c2 & 1) * 16 + cb;
    #pragma unroll
    for (int i = 0; i < 4; ++i) {
      d0[(qr * 4 + i) * 40] = f2bf(cA[c2][i]);
      d1[(qr * 4 + i) * 40] = f2bf(cB[c2][i]);
    }
  }

  // ---- Phase 3: ctx = tanh(combined @ W_ctx + b_ctx), K=64, staged ----
  __syncthreads();                      // phase-2 stg readers done
  {
    const u16* src = WctxF + tid * 8;
    short8 s0 = *(const short8*)(src);
    short8 s1 = *(const short8*)(src + 2048);
    short8 s2 = *(const short8*)(src + 4096);
    short8 s3 = *(const short8*)(src + 6144);
    *(short8*)(stg + tid * 8) = s0;
    *(short8*)(stg + 2048 + tid * 8) = s1;
    *(short8*)(stg + 4096 + tid * 8) = s2;
    *(short8*)(stg + 6144 + tid * 8) = s3;
  }
  __syncthreads();
  f32x4 c30[8], c31[8];
  #pragma unroll
  for (int i = 0; i < 8; ++i) { c30[i] = vz; c31[i] = vz; }
  #pragma unroll
  for (int kt = 0; kt < 2; ++kt) {
    short8 A0 = *(const short8*)(cmb0 + kt * 640 + cb * 40 + qr * 8);
    short8 A1 = *(const short8*)(cmb1 + kt * 640 + cb * 40 + qr * 8);
    #pragma unroll
    for (int ct = 0; ct < 8; ++ct) {
      short8 Bf = *(const short8*)(stg + (kt * 8 + ct) * 512 + ln * 8);
      c30[ct] = __builtin_amdgcn_mfma_f32_16x16x32_bf16(A0, Bf, c30[ct], 0, 0, 0);
      c31[ct] = __builtin_amdgcn_mfma_f32_16x16x32_bf16(A1, Bf, c31[ct], 0, 0, 0);
    }
  }
  #pragma unroll
  for (int ct = 0; ct < 8; ++ct) {
    float bc = b_ctx[ct * 16 + cb];
    u16* d0 = ctx0 + ct * 16 + cb;
    u16* d1 = ctx1 + ct * 16 + cb;
    #pragma unroll
    for (int i = 0; i < 4; ++i) {
      float v0 = c30[ct][i] + bc;
      float e0 = __expf(2.f * v0);           // tanh via exp; saturates correctly
      d0[(qr * 4 + i) * 136] = f2bf(1.f - 2.f / (e0 + 1.f));
      float v1 = c31[ct][i] + bc;
      float e1 = __expf(2.f * v1);
      d1[(qr * 4 + i) * 136] = f2bf(1.f - 2.f / (e1 + 1.f));
    }
  }

  // ---- Phase 4: logits = ctx @ W_out + b_out (MFMA, N padded to 16) ----
  __syncthreads();                      // phase-3 stg readers done
  {
    short8 s0 = *(const short8*)(WoutF + tid * 8);   // 2048 u16 total
    *(short8*)(stg + tid * 8) = s0;
  }
  __syncthreads();
  f32x4 a40 = vz, a41 = vz;
  #pragma unroll
  for (int kt = 0; kt < 4; ++kt) {
    short8 A0 = *(const short8*)(ctx0 + cb * 136 + kt * 32 + qr * 8);
    short8 A1 = *(const short8*)(ctx1 + cb * 136 + kt * 32 + qr * 8);
    short8 Bf = *(const short8*)(stg + kt * 512 + ln * 8);
    a40 = __builtin_amdgcn_mfma_f32_16x16x32_bf16(A0, Bf, a40, 0, 0, 0);
    a41 = __builtin_amdgcn_mfma_f32_16x16x32_bf16(A1, Bf, a41, 0, 0, 0);
  }
  if (cb < 3) {
    float bo = b_out[cb];
    #pragma unroll
    for (int i = 0; i < 4; ++i) {
      out[(size_t)(grow + qr * 4 + i) * 3 + cb] = a40[i] + bo;
      out[(size_t)(grow + 16 + qr * 4 + i) * 3 + cb] = a41[i] + bo;
    }
  }
}

extern "C" void kernel_launch(void* const* d_in, const int* in_sizes, int n_in,
                              void* d_out, int out_size, void* d_ws, size_t ws_size,
                              hipStream_t stream) {
  const float* x      = (const float*)d_in[0];
  const float* W_in   = (const float*)d_in[1];
  const float* b_in   = (const float*)d_in[2];
  const float* W_gate = (const float*)d_in[3];
  const float* b_gate = (const float*)d_in[4];
  const float* W_exp  = (const float*)d_in[5];
  const float* b_exp  = (const float*)d_in[6];
  const float* W_ctx  = (const float*)d_in[7];
  const float* b_ctx  = (const float*)d_in[8];
  const float* W_out  = (const float*)d_in[9];
  const float* b_out  = (const float*)d_in[10];
  float* out = (float*)d_out;

  char* ws = (char*)d_ws;
  float* wm  = (float*)(ws + OFF_WM);
  u16* WinF  = (u16*)(ws + OFF_WINF);
  u16* WegF  = (u16*)(ws + OFF_WEGF);
  u16* WctxF = (u16*)(ws + OFF_WCTXF);
  u16* WoutF = (u16*)(ws + OFF_WOUTF);

  const int B = in_sizes[0] / 784;
  prep_kernel<<<648, 256, 0, stream>>>(W_in, b_in, W_gate, W_exp, W_ctx, W_out,
                                       wm, WinF, WegF, WctxF, WoutF);
  fused_kernel<<<B / 128, 256, 0, stream>>>(x, b_in, b_gate, b_exp, b_ctx, b_out,
                                            wm, WinF, WegF, WctxF, WoutF, out);
}